// Round 11
// baseline (2635.640 us; speedup 1.0000x reference)
//
#include <hip/hip_runtime.h>
#include <math.h>

#define BATCH  64
#define TSTEPS 2048
#define EMBED  300
#define HID    256
#define GATES  1024  // 4*HID
#define WROWSTR 138   // dwords per W-LDS row (4 quarters x 34 + 2)
#define WQSTR   34    // dwords per quarter (32 data + 2 pad), 8B-aligned
#define HQSTR   36    // dwords per h quarter (32 data + 4 pad), 16B-aligned

typedef __fp16 h2 __attribute__((ext_vector_type(2)));   // matches cvt_pkrtz/fdot2

__device__ __forceinline__ h2 pack_h2(float a, float b) {
    return __builtin_amdgcn_cvt_pkrtz(a, b);
}
__device__ __forceinline__ h2 bc_h2(unsigned u) {
    return __builtin_bit_cast(h2, u);
}
__device__ __forceinline__ float dot2f(h2 w, h2 h, float acc) {
#if __has_builtin(__builtin_amdgcn_fdot2)
    return __builtin_amdgcn_fdot2(w, h, acc, false);   // f32 accumulate
#else
    return acc + (float)w[0]*(float)h[0] + (float)w[1]*(float)h[1];
#endif
}
__device__ __forceinline__ float rcpf_(float x) {
#if __has_builtin(__builtin_amdgcn_rcpf)
    return __builtin_amdgcn_rcpf(x);
#else
    return 1.0f / x;
#endif
}
__device__ __forceinline__ float sigm_(float x) { return rcpf_(1.f + __expf(-x)); }
__device__ __forceinline__ float tanh_(float x) { return 1.f - 2.f*rcpf_(__expf(2.f*x) + 1.f); }

// ---------------- Kernel 1: per-chunk compaction of update steps ------------
__global__ __launch_bounds__(256) void k_compact(
    const float* __restrict__ mask, const int* __restrict__ lengths,
    int* __restrict__ list, int* __restrict__ cnt,
    float* __restrict__ h_state, float* __restrict__ c_state,
    int t0, int CT, int first_chunk)
{
    int b = blockIdx.x, tid = threadIdx.x;
    if (first_chunk) {
        h_state[b*HID + tid] = 0.f;   // blockDim == HID
        c_state[b*HID + tid] = 0.f;
    }
    int idx = lengths[b] - 1;
    idx = idx < 0 ? 0 : (idx > TSTEPS-1 ? TSTEPS-1 : idx);

    __shared__ int wcnt[4];
    __shared__ int running;
    if (tid == 0) running = 0;
    __syncthreads();

    for (int base = 0; base < CT; base += 256) {
        int t = t0 + base + tid;
        bool pred = ((base + tid) < CT) && (t <= idx)
                    && (mask[b*TSTEPS + t] >= 0.5f);
        unsigned long long bal = __ballot(pred);
        int wave = tid >> 6, lane = tid & 63;
        if (lane == 0) wcnt[wave] = __popcll(bal);
        __syncthreads();
        int off = running;
        for (int w2 = 0; w2 < wave; ++w2) off += wcnt[w2];
        off += __popcll(bal & ((1ull << lane) - 1ull));
        if (pred) list[b*CT + off] = t;
        __syncthreads();
        if (tid == 0) running += wcnt[0] + wcnt[1] + wcnt[2] + wcnt[3];
        __syncthreads();
    }
    if (tid == 0) cnt[b] = running;
}

// ---------------- Kernel 2: gathered GEMM  Z[b,j,:] = x[b,t_j,:] @ W_ih^T ---
__global__ __launch_bounds__(256) void k_gemm(
    const float* __restrict__ emb, const float* __restrict__ W_ih,
    const int* __restrict__ list, const int* __restrict__ cnt,
    float* __restrict__ Z, int CT)
{
    int b = blockIdx.z;
    int mb = cnt[b];
    int i0 = blockIdx.y * 64;
    if (i0 >= mb) return;
    int n0 = blockIdx.x * 64;
    int tid = threadIdx.x;

    __shared__ float As[64][65];
    __shared__ float Bs[64][65];
    __shared__ int   tl[64];

    if (tid < 64) {
        int j = i0 + tid;
        tl[tid] = (j < mb) ? list[b*CT + j] : 0;
    }
    __syncthreads();

    float acc[4][4] = {};
    int tr = tid >> 4, tc = tid & 15;

    for (int k0 = 0; k0 < EMBED; k0 += 64) {
        #pragma unroll
        for (int e = 0; e < 16; ++e) {
            int flat = tid + 256*e;
            int r = flat >> 6, k = flat & 63;
            int j = i0 + r;
            float va = 0.f, vb = 0.f;
            if (k0 + k < EMBED) {
                if (j < mb)
                    va = emb[((size_t)(b*TSTEPS + tl[r]))*EMBED + k0 + k];
                vb = W_ih[(size_t)(n0 + r)*EMBED + k0 + k];
            }
            As[r][k] = va;
            Bs[r][k] = vb;
        }
        __syncthreads();
        #pragma unroll 8
        for (int k = 0; k < 64; ++k) {
            float a0 = As[tr*4+0][k], a1 = As[tr*4+1][k];
            float a2 = As[tr*4+2][k], a3 = As[tr*4+3][k];
            float b0 = Bs[tc*4+0][k], b1 = Bs[tc*4+1][k];
            float b2 = Bs[tc*4+2][k], b3 = Bs[tc*4+3][k];
            acc[0][0] += a0*b0; acc[0][1] += a0*b1; acc[0][2] += a0*b2; acc[0][3] += a0*b3;
            acc[1][0] += a1*b0; acc[1][1] += a1*b1; acc[1][2] += a1*b2; acc[1][3] += a1*b3;
            acc[2][0] += a2*b0; acc[2][1] += a2*b1; acc[2][2] += a2*b2; acc[2][3] += a2*b3;
            acc[3][0] += a3*b0; acc[3][1] += a3*b1; acc[3][2] += a3*b2; acc[3][3] += a3*b3;
        }
        __syncthreads();
    }

    #pragma unroll
    for (int e = 0; e < 4; ++e) {
        int j = i0 + tr*4 + e;
        if (j < mb) {
            size_t zb = ((size_t)b*CT + j)*GATES + n0 + tc*4;
            Z[zb+0] = acc[e][0]; Z[zb+1] = acc[e][1];
            Z[zb+2] = acc[e][2]; Z[zb+3] = acc[e][3];
        }
    }
}

// ---------------- Kernel 3: recurrent LSTM — ONE block per batch, K-split-4 -
// 512 threads. Thread (rt=tid>>2, qs=tid&3) computes K-quarter [64qs,64qs+64)
// partial dots for the 8 rows {rt+128m, m=0..7} = ALL 4 gates of dims rt and
// rt+128. Two shfl_xor butterflies (lanes qs adjacent in-wave) complete the
// dots -> cell update local, NO act exchange, ONE barrier/step. h-LDS traffic
// drops 262KB->65KB/step (was the 65% LDS-BW bottleneck). W: m=0..5 in regs
// (192 h2, same proven budget as r9), m=6,7 (o-gate) in LDS. z+bias folded
// pre-reduce by lane qs into p[2qs],p[2qs+1]. Named scalars p0..p7 (no
// runtime-indexed arrays -> no scratch). No spin loops anywhere: the only
// sync is uniform __syncthreads.
__global__ __launch_bounds__(512, 2) void k_lstm(
    const float* __restrict__ Z, const int* __restrict__ cnt,
    const float* __restrict__ W_hh,
    const float* __restrict__ b_ih, const float* __restrict__ b_hh,
    float* __restrict__ h_state, float* __restrict__ c_state, int CT)
{
    int b   = blockIdx.x;
    int tid = threadIdx.x;        // 0..511
    int qs  = tid & 3;            // K-quarter
    int rt  = tid >> 2;           // 0..127: owns dims rt and rt+128

    __shared__ unsigned wlds[256 * WROWSTR];       // o-gate rows 768..1023, f16
    __shared__ __align__(16) unsigned h16dw[2 * 4 * HQSTR];  // 2 bufs x 4 qtr

    // ---- stage W rows 768..1023 into LDS as f16 pairs ----------------------
    for (int idx = tid; idx < 256*128; idx += 512) {   // 128 h2 per row
        int r = idx >> 7, kp = idx & 127;
        int qsp = kp >> 5, o = kp & 31;
        float2 v = ((const float2*)(W_hh + (size_t)(768 + r)*HID))[kp];
        *(h2*)&wlds[r*WROWSTR + qsp*WQSTR + o] = pack_h2(v.x, v.y);
    }
    // ---- W rows m=0..5, quarter qs, into registers: 6 x 32 h2 --------------
    h2 wr[6][32];
    #pragma unroll
    for (int m = 0; m < 6; ++m) {
        const float2* pw = (const float2*)(W_hh + (size_t)(rt + 128*m)*HID) + qs*32;
        #pragma unroll
        for (int jj = 0; jj < 32; ++jj) wr[m][jj] = pack_h2(pw[jj].x, pw[jj].y);
    }
    int rA = rt + 256*qs, rB = rA + 128;       // rows this lane seeds z+bias for
    float biasA = b_ih[rA] + b_hh[rA];
    float biasB = b_ih[rB] + b_hh[rB];

    _Float16* hf = (_Float16*)h16dw;           // f16 view; buffer stride 288
    float c0 = c_state[(size_t)b*HID + rt];
    float c1 = c_state[(size_t)b*HID + rt + 128];
    if (tid < 256)
        hf[(tid >> 6)*(2*HQSTR) + (tid & 63)] = (_Float16)h_state[(size_t)b*HID + tid];
    __syncthreads();

    int mb = cnt[b];
    float zA = (mb > 0) ? Z[((size_t)b*CT)*GATES + rA] : 0.f;
    float zB = (mb > 0) ? Z[((size_t)b*CT)*GATES + rB] : 0.f;
    int bf = 0;

    for (int j = 0; j < mb; ++j) {
        float zAn = 0.f, zBn = 0.f;
        if (j + 1 < mb) {
            zAn = Z[((size_t)b*CT + j + 1)*GATES + rA];
            zBn = Z[((size_t)b*CT + j + 1)*GATES + rB];
        }
        const uint4* hq  = (const uint4*)&h16dw[bf*(4*HQSTR) + qs*HQSTR];
        const unsigned* w6 = &wlds[(size_t)rt*WROWSTR + qs*WQSTR];
        const unsigned* w7 = &wlds[(size_t)(rt+128)*WROWSTR + qs*WQSTR];

        float p0=0.f,p1=0.f,p2=0.f,p3=0.f,p4=0.f,p5=0.f,p6=0.f,p7=0.f;
        #pragma unroll
        for (int c = 0; c < 8; ++c) {
            uint4 hv = hq[c];                      // 8 f16 of this K-quarter
            h2 h0 = bc_h2(hv.x), h1 = bc_h2(hv.y);
            h2 hx = bc_h2(hv.z), h3 = bc_h2(hv.w);
            p0 = dot2f(wr[0][4*c+0], h0, p0); p0 = dot2f(wr[0][4*c+1], h1, p0);
            p0 = dot2f(wr[0][4*c+2], hx, p0); p0 = dot2f(wr[0][4*c+3], h3, p0);
            p1 = dot2f(wr[1][4*c+0], h0, p1); p1 = dot2f(wr[1][4*c+1], h1, p1);
            p1 = dot2f(wr[1][4*c+2], hx, p1); p1 = dot2f(wr[1][4*c+3], h3, p1);
            p2 = dot2f(wr[2][4*c+0], h0, p2); p2 = dot2f(wr[2][4*c+1], h1, p2);
            p2 = dot2f(wr[2][4*c+2], hx, p2); p2 = dot2f(wr[2][4*c+3], h3, p2);
            p3 = dot2f(wr[3][4*c+0], h0, p3); p3 = dot2f(wr[3][4*c+1], h1, p3);
            p3 = dot2f(wr[3][4*c+2], hx, p3); p3 = dot2f(wr[3][4*c+3], h3, p3);
            p4 = dot2f(wr[4][4*c+0], h0, p4); p4 = dot2f(wr[4][4*c+1], h1, p4);
            p4 = dot2f(wr[4][4*c+2], hx, p4); p4 = dot2f(wr[4][4*c+3], h3, p4);
            p5 = dot2f(wr[5][4*c+0], h0, p5); p5 = dot2f(wr[5][4*c+1], h1, p5);
            p5 = dot2f(wr[5][4*c+2], hx, p5); p5 = dot2f(wr[5][4*c+3], h3, p5);
            uint2 wa0 = *(const uint2*)&w6[4*c];
            uint2 wa1 = *(const uint2*)&w6[4*c+2];
            uint2 wb0 = *(const uint2*)&w7[4*c];
            uint2 wb1 = *(const uint2*)&w7[4*c+2];
            p6 = dot2f(bc_h2(wa0.x), h0, p6); p6 = dot2f(bc_h2(wa0.y), h1, p6);
            p6 = dot2f(bc_h2(wa1.x), hx, p6); p6 = dot2f(bc_h2(wa1.y), h3, p6);
            p7 = dot2f(bc_h2(wb0.x), h0, p7); p7 = dot2f(bc_h2(wb0.y), h1, p7);
            p7 = dot2f(bc_h2(wb1.x), hx, p7); p7 = dot2f(bc_h2(wb1.y), h3, p7);
        }
        // fold z+bias exactly once (lane qs seeds rows R(2qs), R(2qs+1))
        float zb0 = zA + biasA, zb1 = zB + biasB;
        p0 += (qs==0) ? zb0 : 0.f;  p1 += (qs==0) ? zb1 : 0.f;
        p2 += (qs==1) ? zb0 : 0.f;  p3 += (qs==1) ? zb1 : 0.f;
        p4 += (qs==2) ? zb0 : 0.f;  p5 += (qs==2) ? zb1 : 0.f;
        p6 += (qs==3) ? zb0 : 0.f;  p7 += (qs==3) ? zb1 : 0.f;
        // butterfly over the 4 K-quarters (lanes qs adjacent in-wave)
        p0 += __shfl_xor(p0, 1); p0 += __shfl_xor(p0, 2);
        p1 += __shfl_xor(p1, 1); p1 += __shfl_xor(p1, 2);
        p2 += __shfl_xor(p2, 1); p2 += __shfl_xor(p2, 2);
        p3 += __shfl_xor(p3, 1); p3 += __shfl_xor(p3, 2);
        p4 += __shfl_xor(p4, 1); p4 += __shfl_xor(p4, 2);
        p5 += __shfl_xor(p5, 1); p5 += __shfl_xor(p5, 2);
        p6 += __shfl_xor(p6, 1); p6 += __shfl_xor(p6, 2);
        p7 += __shfl_xor(p7, 1); p7 += __shfl_xor(p7, 2);
        // cell update for dims rt (p0,p2,p4,p6) and rt+128 (p1,p3,p5,p7)
        float i0 = sigm_(p0), f0 = sigm_(p2), g0 = tanh_(p4), o0 = sigm_(p6);
        c0 = f0*c0 + i0*g0;
        float h0n = o0 * tanh_(c0);
        float i1 = sigm_(p1), f1 = sigm_(p3), g1 = tanh_(p5), o1 = sigm_(p7);
        c1 = f1*c1 + i1*g1;
        float h1n = o1 * tanh_(c1);
        int nb = bf ^ 1;
        if (qs == 0) {
            hf[nb*(4*HQSTR*2) + (rt >> 6)*(2*HQSTR) + (rt & 63)] = (_Float16)h0n;
            hf[nb*(4*HQSTR*2) + ((rt >> 6) + 2)*(2*HQSTR) + (rt & 63)] = (_Float16)h1n;
        }
        __syncthreads();     // the ONLY barrier per step
        bf = nb;
        zA = zAn; zB = zBn;
    }

    if (qs == 0) {
        c_state[(size_t)b*HID + rt]       = c0;
        c_state[(size_t)b*HID + rt + 128] = c1;
    }
    if (tid < 256)
        h_state[(size_t)b*HID + tid] =
            (float)hf[bf*(4*HQSTR*2) + (tid >> 6)*(2*HQSTR) + (tid & 63)];
}

// ---------------- Kernel 4: logits -> softmax -> argmax ---------------------
__global__ __launch_bounds__(64) void k_final(
    const float* __restrict__ h_state, const float* __restrict__ W_out,
    const float* __restrict__ b_out, float* __restrict__ out)
{
    int b = threadIdx.x;   // 64 threads
    float l0 = b_out[0], l1 = b_out[1];
    for (int k = 0; k < HID; ++k) {
        float h = h_state[b*HID + k];
        l0 += h * W_out[k];
        l1 += h * W_out[HID + k];
    }
    float m  = fmaxf(l0, l1);
    float e0 = expf(l0 - m), e1 = expf(l1 - m);
    float s  = e0 + e1;
    float p0 = e0 / s, p1 = e1 / s;
    out[b*2 + 0] = p0;
    out[b*2 + 1] = p1;
    out[BATCH*2 + b] = (p1 > p0) ? 1.0f : 0.0f;  // argmax, first-index tiebreak
}

// ---------------- host ------------------------------------------------------
extern "C" void kernel_launch(void* const* d_in, const int* in_sizes, int n_in,
                              void* d_out, int out_size, void* d_ws, size_t ws_size,
                              hipStream_t stream)
{
    (void)in_sizes; (void)n_in; (void)out_size;
    const float* emb   = (const float*)d_in[0];
    const float* mask  = (const float*)d_in[1];
    const int*   len   = (const int*)  d_in[2];
    const float* W_ih  = (const float*)d_in[3];
    const float* W_hh  = (const float*)d_in[4];
    const float* b_ih  = (const float*)d_in[5];
    const float* b_hh  = (const float*)d_in[6];
    const float* W_out = (const float*)d_in[7];
    const float* b_out = (const float*)d_in[8];
    float* out = (float*)d_out;

    char* p = (char*)d_ws;
    auto carve = [&](size_t bytes) -> char* {
        char* r = p;
        p += (bytes + 255) & ~(size_t)255;
        return r;
    };
    float* h_state = (float*)carve((size_t)BATCH*HID*4);
    float* c_state = (float*)carve((size_t)BATCH*HID*4);
    int*   cntb    = (int*)  carve((size_t)BATCH*4);

    size_t fixed = (size_t)(p - (char*)d_ws);
    int CT = TSTEPS;  // shrink to fit workspace
    while (CT > 64) {
        size_t lb = (((size_t)BATCH*CT*4) + 255) & ~(size_t)255;
        size_t zb = (size_t)BATCH*CT*GATES*4;
        if (fixed + lb + zb + 1024 <= ws_size) break;
        CT >>= 1;
    }
    int*   list = (int*)  carve((size_t)BATCH*CT*4);
    float* Z    = (float*)carve((size_t)BATCH*CT*GATES*4);

    int nchunks = TSTEPS / CT;
    for (int c = 0; c < nchunks; ++c) {
        int t0 = c * CT;
        int first = (c == 0) ? 1 : 0;
        hipLaunchKernelGGL(k_compact, dim3(BATCH), dim3(256), 0, stream,
                           mask, len, list, cntb, h_state, c_state,
                           t0, CT, first);
        hipLaunchKernelGGL(k_gemm, dim3(16, CT/64, BATCH), dim3(256), 0, stream,
                           emb, W_ih, list, cntb, Z, CT);
        hipLaunchKernelGGL(k_lstm, dim3(BATCH), dim3(512), 0, stream,
                           Z, cntb, W_hh, b_ih, b_hh,
                           h_state, c_state, CT);
    }
    hipLaunchKernelGGL(k_final, dim3(1), dim3(64), 0, stream,
                       h_state, W_out, b_out, out);
}

// Round 12
// 2280.563 us; speedup vs baseline: 1.1557x; 1.1557x over previous
//
#include <hip/hip_runtime.h>
#include <math.h>

#define BATCH  64
#define TSTEPS 2048
#define EMBED  300
#define HID    256
#define GATES  1024  // 4*HID
#define WSTRIDE 34   // dwords per row of LDS-resident W half (64 f16 = 32 dw + 2 pad)
#define ASTR   328   // f16 stride of k_gemm staged tiles (300 data + 28 pad)

typedef __fp16 h2 __attribute__((ext_vector_type(2)));   // matches cvt_pkrtz/fdot2
typedef __fp16 h4 __attribute__((ext_vector_type(4)));
typedef __fp16 h8 __attribute__((ext_vector_type(8)));
typedef float  f4 __attribute__((ext_vector_type(4)));

__device__ __forceinline__ h2 pack_h2(float a, float b) {
    return __builtin_amdgcn_cvt_pkrtz(a, b);
}
__device__ __forceinline__ h2 bc_h2(unsigned u) {
    return __builtin_bit_cast(h2, u);
}
__device__ __forceinline__ float dot2f(h2 w, h2 h, float acc) {
#if __has_builtin(__builtin_amdgcn_fdot2)
    return __builtin_amdgcn_fdot2(w, h, acc, false);   // f32 accumulate
#else
    return acc + (float)w[0]*(float)h[0] + (float)w[1]*(float)h[1];
#endif
}
__device__ __forceinline__ float rcpf_(float x) {
#if __has_builtin(__builtin_amdgcn_rcpf)
    return __builtin_amdgcn_rcpf(x);
#else
    return 1.0f / x;
#endif
}
__device__ __forceinline__ float sigm_(float x) { return rcpf_(1.f + __expf(-x)); }
__device__ __forceinline__ float tanh_(float x) { return 1.f - 2.f*rcpf_(__expf(2.f*x) + 1.f); }

// ---------------- Kernel 1: per-chunk compaction of update steps ------------
__global__ __launch_bounds__(256) void k_compact(
    const float* __restrict__ mask, const int* __restrict__ lengths,
    int* __restrict__ list, int* __restrict__ cnt,
    float* __restrict__ h_state, float* __restrict__ c_state,
    int t0, int CT, int first_chunk)
{
    int b = blockIdx.x, tid = threadIdx.x;
    if (first_chunk) {
        h_state[b*HID + tid] = 0.f;   // blockDim == HID
        c_state[b*HID + tid] = 0.f;
    }
    int idx = lengths[b] - 1;
    idx = idx < 0 ? 0 : (idx > TSTEPS-1 ? TSTEPS-1 : idx);

    __shared__ int wcnt[4];
    __shared__ int running;
    if (tid == 0) running = 0;
    __syncthreads();

    for (int base = 0; base < CT; base += 256) {
        int t = t0 + base + tid;
        bool pred = ((base + tid) < CT) && (t <= idx)
                    && (mask[b*TSTEPS + t] >= 0.5f);
        unsigned long long bal = __ballot(pred);
        int wave = tid >> 6, lane = tid & 63;
        if (lane == 0) wcnt[wave] = __popcll(bal);
        __syncthreads();
        int off = running;
        for (int w2 = 0; w2 < wave; ++w2) off += wcnt[w2];
        off += __popcll(bal & ((1ull << lane) - 1ull));
        if (pred) list[b*CT + off] = t;
        __syncthreads();
        if (tid == 0) running += wcnt[0] + wcnt[1] + wcnt[2] + wcnt[3];
        __syncthreads();
    }
    if (tid == 0) cnt[b] = running;
}

// ---------------- Kernel 2: gathered GEMM via MFMA 16x16x32 f16 -------------
// Z[b,j,:] = x[b,t_j,:] @ W_ih^T. Tile: M=64 gathered rows x N=128 gate rows,
// K=300 padded to 320 (10 K-steps). 256 threads = 4 waves; wave w owns rows
// [16w,16w+16), 8 N-subtiles each. A/B staged f16 in LDS (stride 328 f16 ->
// <=2-way banks). Frag layouts: C/D col=lane&15,row=(lane>>4)*4+reg (m89);
// A/B half-split: elems 0-3 k=4*(l>>4)+j, elems 4-7 at +16 (m162 tr-read).
__global__ __launch_bounds__(256) void k_gemm(
    const float* __restrict__ emb, const float* __restrict__ W_ih,
    const int* __restrict__ list, const int* __restrict__ cnt,
    float* __restrict__ Z, int CT)
{
    int b = blockIdx.z;
    int mb = cnt[b];
    int i0 = blockIdx.y * 64;
    if (i0 >= mb) return;
    int n0 = blockIdx.x * 128;
    int tid = threadIdx.x;
    int w = tid >> 6, l = tid & 63;

    __shared__ _Float16 Al[64 * ASTR];     // 41,984 B
    __shared__ _Float16 Bl[128 * ASTR];    // 83,968 B
    __shared__ int tl[64];

    if (tid < 64) {
        int j = i0 + tid;
        tl[tid] = (j < mb) ? list[b*CT + j] : -1;
    }
    __syncthreads();

    // stage A (gathered emb rows) as f16: 64 rows x 300, float4-wide
    for (int idx = tid; idx < 64*75; idx += 256) {
        int r = idx / 75, c = idx - 75*r;
        float4 v = {0.f, 0.f, 0.f, 0.f};
        int trow = tl[r];
        if (trow >= 0)
            v = ((const float4*)(emb + ((size_t)b*TSTEPS + trow)*EMBED))[c];
        *(h2*)&Al[r*ASTR + 4*c]     = pack_h2(v.x, v.y);
        *(h2*)&Al[r*ASTR + 4*c + 2] = pack_h2(v.z, v.w);
    }
    for (int idx = tid; idx < 64*14; idx += 256) {      // zero-pad k 300..327
        int r = idx / 14, c2 = idx - 14*r;
        *(unsigned*)&Al[r*ASTR + 300 + 2*c2] = 0u;
    }
    // stage B = W_ih rows n0..n0+127 as f16
    for (int idx = tid; idx < 128*75; idx += 256) {
        int r = idx / 75, c = idx - 75*r;
        float4 v = ((const float4*)(W_ih + (size_t)(n0 + r)*EMBED))[c];
        *(h2*)&Bl[r*ASTR + 4*c]     = pack_h2(v.x, v.y);
        *(h2*)&Bl[r*ASTR + 4*c + 2] = pack_h2(v.z, v.w);
    }
    for (int idx = tid; idx < 128*14; idx += 256) {
        int r = idx / 14, c2 = idx - 14*r;
        *(unsigned*)&Bl[r*ASTR + 300 + 2*c2] = 0u;
    }
    __syncthreads();

    int arow = w*16 + (l & 15);
    int kg4  = (l >> 4) * 4;

    f4 acc[8];
    #pragma unroll
    for (int nt = 0; nt < 8; ++nt) acc[nt] = f4{0.f, 0.f, 0.f, 0.f};

    #pragma unroll 2
    for (int ks = 0; ks < 10; ++ks) {
        int kb = ks*32 + kg4;
        h4 alo = *(const h4*)&Al[arow*ASTR + kb];
        h4 ahi = *(const h4*)&Al[arow*ASTR + kb + 16];
        h8 af = __builtin_shufflevector(alo, ahi, 0,1,2,3,4,5,6,7);
        #pragma unroll
        for (int nt = 0; nt < 8; ++nt) {
            int brow = nt*16 + (l & 15);
            h4 blo = *(const h4*)&Bl[brow*ASTR + kb];
            h4 bhi = *(const h4*)&Bl[brow*ASTR + kb + 16];
            h8 bf = __builtin_shufflevector(blo, bhi, 0,1,2,3,4,5,6,7);
            acc[nt] = __builtin_amdgcn_mfma_f32_16x16x32_f16(af, bf, acc[nt], 0, 0, 0);
        }
    }

    int drow0 = w*16 + (l >> 4)*4;
    #pragma unroll
    for (int nt = 0; nt < 8; ++nt) {
        #pragma unroll
        for (int j = 0; j < 4; ++j) {
            int r = drow0 + j;
            if (i0 + r < mb)
                Z[((size_t)b*CT + i0 + r)*GATES + n0 + nt*16 + (l & 15)] = acc[nt][j];
        }
    }
}

// ---------------- Kernel 3: recurrent LSTM — ONE block per batch ------------
// EXACT round-9 code (measured 1910us, 0 bank conflicts, no scratch, VGPR 128).
// 512 threads; thread i owns gate-rows {i, 512+i}. W_hh f16: k<64 in LDS
// (WSTRIDE 34, uint2 reads), k in [64,256) as 2x96 h2 register/AGPR-resident.
// Native v_exp/v_rcp activations.
__global__ __launch_bounds__(512, 2) void k_lstm(
    const float* __restrict__ Z, const int* __restrict__ cnt,
    const float* __restrict__ W_hh,
    const float* __restrict__ b_ih, const float* __restrict__ b_hh,
    float* __restrict__ h_state, float* __restrict__ c_state, int CT)
{
    int b = blockIdx.x;
    int tid = threadIdx.x;            // 0..511
    int d   = tid & 255;              // hidden dim this thread's rows act on
    int rowA = tid;                   // gate (tid>>8)      : 0 or 1
    int rowB = tid + 512;             // gate (tid>>8) + 2  : 2 or 3

    __shared__ unsigned wlds[1024 * WSTRIDE];        // 139,264 B
    __shared__ float act13[2][256];                  // forget, out broadcast
    __shared__ __align__(16) _Float16 h_arr[HID];    // current h (f16)

    // ---- stage W[k<64] into LDS as f16 pairs --------------------------------
    for (int idx = tid; idx < 1024*32; idx += 512) {
        int r = idx >> 5, k = idx & 31;              // k = half2 index (f16 2k,2k+1)
        float2 v = ((const float2*)(W_hh + (size_t)r*HID))[k];
        *(h2*)&wlds[r*WSTRIDE + k] = pack_h2(v.x, v.y);
    }

    // ---- W[k in 64..255] into registers: 96 half2 per row -------------------
    h2 wrA[96], wrB[96];
    {
        const float2* pA = (const float2*)(W_hh + (size_t)rowA*HID);
        const float2* pB = (const float2*)(W_hh + (size_t)rowB*HID);
        #pragma unroll
        for (int t = 0; t < 96; ++t) {
            float2 va = pA[32 + t], vb = pB[32 + t];
            wrA[t] = pack_h2(va.x, va.y);
            wrB[t] = pack_h2(vb.x, vb.y);
        }
    }
    float biasA = b_ih[rowA] + b_hh[rowA];
    float biasB = b_ih[rowB] + b_hh[rowB];

    float c_reg = 0.f;
    if (tid < 256) {
        h_arr[d] = (_Float16)h_state[(size_t)b*HID + d];
        c_reg    = c_state[(size_t)b*HID + d];
    }
    __syncthreads();

    int mb = cnt[b];
    float zAcur = 0.f, zBcur = 0.f;
    if (mb > 0) {
        zAcur = Z[((size_t)b*CT)*GATES + rowA];
        zBcur = Z[((size_t)b*CT)*GATES + rowB];
    }

    for (int j = 0; j < mb; ++j) {
        // prefetch next step's z under the dot
        float zAn = 0.f, zBn = 0.f;
        if (j + 1 < mb) {
            zAn = Z[((size_t)b*CT + j + 1)*GATES + rowA];
            zBn = Z[((size_t)b*CT + j + 1)*GATES + rowB];
        }

        float accA0 = 0.f, accA1 = 0.f, accB0 = 0.f, accB1 = 0.f;
        #pragma unroll
        for (int c = 0; c < 32; ++c) {
            uint4 hv = ((const uint4*)h_arr)[c];     // 8 f16 of h (broadcast)
            h2 h0 = bc_h2(hv.x), h1 = bc_h2(hv.y);
            h2 h2_ = bc_h2(hv.z), h3 = bc_h2(hv.w);
            h2 wA0, wA1, wA2, wA3, wB0, wB1, wB2, wB3;
            if (c < 8) {
                uint2 a01 = *(const uint2*)&wlds[rowA*WSTRIDE + 4*c];
                uint2 a23 = *(const uint2*)&wlds[rowA*WSTRIDE + 4*c + 2];
                uint2 b01 = *(const uint2*)&wlds[rowB*WSTRIDE + 4*c];
                uint2 b23 = *(const uint2*)&wlds[rowB*WSTRIDE + 4*c + 2];
                wA0 = bc_h2(a01.x); wA1 = bc_h2(a01.y);
                wA2 = bc_h2(a23.x); wA3 = bc_h2(a23.y);
                wB0 = bc_h2(b01.x); wB1 = bc_h2(b01.y);
                wB2 = bc_h2(b23.x); wB3 = bc_h2(b23.y);
            } else {
                int t = (c - 8) * 4;
                wA0 = wrA[t+0]; wA1 = wrA[t+1]; wA2 = wrA[t+2]; wA3 = wrA[t+3];
                wB0 = wrB[t+0]; wB1 = wrB[t+1]; wB2 = wrB[t+2]; wB3 = wrB[t+3];
            }
            accA0 = dot2f(wA0, h0, accA0);
            accA1 = dot2f(wA1, h1, accA1);
            accA0 = dot2f(wA2, h2_, accA0);
            accA1 = dot2f(wA3, h3, accA1);
            accB0 = dot2f(wB0, h0, accB0);
            accB1 = dot2f(wB1, h1, accB1);
            accB0 = dot2f(wB2, h2_, accB0);
            accB1 = dot2f(wB3, h3, accB1);
        }
        float aF = zAcur + biasA + (accA0 + accA1);   // gate input(i<256)/forget
        float aS = zBcur + biasB + (accB0 + accB1);   // gate cellcand / out

        float iv = 0.f, gv = 0.f;
        if (tid < 256) {
            iv = sigm_(aF);                 // input gate
            gv = tanh_(aS);                 // cell candidate
        } else {
            act13[0][d] = sigm_(aF);        // forget gate
            act13[1][d] = sigm_(aS);        // output gate
        }
        __syncthreads();   // act13 ready; everyone done reading h_arr

        if (tid < 256) {
            float fv = act13[0][d], ov = act13[1][d];
            c_reg = fv * c_reg + iv * gv;
            float hn = ov * tanh_(c_reg);
            h_arr[d] = (_Float16)hn;
        }
        __syncthreads();   // h_arr ready for next step
        zAcur = zAn; zBcur = zBn;
    }

    if (tid < 256) {
        h_state[(size_t)b*HID + d] = (float)h_arr[d];
        c_state[(size_t)b*HID + d] = c_reg;
    }
}

// ---------------- Kernel 4: logits -> softmax -> argmax ---------------------
__global__ __launch_bounds__(64) void k_final(
    const float* __restrict__ h_state, const float* __restrict__ W_out,
    const float* __restrict__ b_out, float* __restrict__ out)
{
    int b = threadIdx.x;   // 64 threads
    float l0 = b_out[0], l1 = b_out[1];
    for (int k = 0; k < HID; ++k) {
        float h = h_state[b*HID + k];
        l0 += h * W_out[k];
        l1 += h * W_out[HID + k];
    }
    float m  = fmaxf(l0, l1);
    float e0 = expf(l0 - m), e1 = expf(l1 - m);
    float s  = e0 + e1;
    float p0 = e0 / s, p1 = e1 / s;
    out[b*2 + 0] = p0;
    out[b*2 + 1] = p1;
    out[BATCH*2 + b] = (p1 > p0) ? 1.0f : 0.0f;  // argmax, first-index tiebreak
}

// ---------------- host ------------------------------------------------------
extern "C" void kernel_launch(void* const* d_in, const int* in_sizes, int n_in,
                              void* d_out, int out_size, void* d_ws, size_t ws_size,
                              hipStream_t stream)
{
    (void)in_sizes; (void)n_in; (void)out_size;
    const float* emb   = (const float*)d_in[0];
    const float* mask  = (const float*)d_in[1];
    const int*   len   = (const int*)  d_in[2];
    const float* W_ih  = (const float*)d_in[3];
    const float* W_hh  = (const float*)d_in[4];
    const float* b_ih  = (const float*)d_in[5];
    const float* b_hh  = (const float*)d_in[6];
    const float* W_out = (const float*)d_in[7];
    const float* b_out = (const float*)d_in[8];
    float* out = (float*)d_out;

    char* p = (char*)d_ws;
    auto carve = [&](size_t bytes) -> char* {
        char* r = p;
        p += (bytes + 255) & ~(size_t)255;
        return r;
    };
    float* h_state = (float*)carve((size_t)BATCH*HID*4);
    float* c_state = (float*)carve((size_t)BATCH*HID*4);
    int*   cntb    = (int*)  carve((size_t)BATCH*4);

    size_t fixed = (size_t)(p - (char*)d_ws);
    int CT = TSTEPS;  // shrink to fit workspace
    while (CT > 64) {
        size_t lb = (((size_t)BATCH*CT*4) + 255) & ~(size_t)255;
        size_t zb = (size_t)BATCH*CT*GATES*4;
        if (fixed + lb + zb + 1024 <= ws_size) break;
        CT >>= 1;
    }
    int*   list = (int*)  carve((size_t)BATCH*CT*4);
    float* Z    = (float*)carve((size_t)BATCH*CT*GATES*4);

    int nchunks = TSTEPS / CT;
    for (int c = 0; c < nchunks; ++c) {
        int t0 = c * CT;
        int first = (c == 0) ? 1 : 0;
        hipLaunchKernelGGL(k_compact, dim3(BATCH), dim3(256), 0, stream,
                           mask, len, list, cntb, h_state, c_state,
                           t0, CT, first);
        hipLaunchKernelGGL(k_gemm, dim3(8, CT/64, BATCH), dim3(256), 0, stream,
                           emb, W_ih, list, cntb, Z, CT);
        hipLaunchKernelGGL(k_lstm, dim3(BATCH), dim3(512), 0, stream,
                           Z, cntb, W_hh, b_ih, b_hh,
                           h_state, c_state, CT);
    }
    hipLaunchKernelGGL(k_final, dim3(1), dim3(64), 0, stream,
                       h_state, W_out, b_out, out);
}